// Round 7
// baseline (412.833 us; speedup 1.0000x reference)
//
#include <hip/hip_runtime.h>
#include <math.h>

#define BINS 30
#define BLOCK 256
#define WGRID 8192                      // wide kernel: 8192 blocks * 256 thr * 8 elem = 2^24
#define GGRID 2048                      // generic fallback grid
#define CPW 16                          // histogram copies per wave (lane & 15)
#define NCOPIES 64                      // 4 waves * 16
#define CSTRIDE 31                      // 30 bins + 1 pad word (bank stagger)
#define GSCALE 32768.0f                 // g in 0.15 fixed point, bits 0..22
#define CNT_ONE (2u << 23)              // +2 per element, count in bits 23..31
#define GMASK 0x7FFFFFu

// d_ws layout: [0..29] u32 counts, [30..59] f32 g-sums

// ---------------- clock diagnostics ----------------
__device__ __forceinline__ unsigned long long memtime_shader() {
    unsigned long long t;
    asm volatile("s_memtime %0\ns_waitcnt lgkmcnt(0)" : "=s"(t) :: "memory");
    return t;
}
__device__ __forceinline__ unsigned long long memtime_real() {
    unsigned long long t;
    asm volatile("s_memrealtime %0\ns_waitcnt lgkmcnt(0)" : "=s"(t) :: "memory");
    return t;
}

// duration_us = ticks / SCLK_MHz  -> reveals effective shader clock
__global__ void spin_shader_clk(unsigned long long ticks) {
    unsigned long long t0 = memtime_shader();
    while (memtime_shader() - t0 < ticks) {}
}

// duration_us = ticks / 100 (RTC is 100 MHz) -> validates the spin mechanism
__global__ void spin_real_clk(unsigned long long ticks) {
    unsigned long long t0 = memtime_real();
    while (memtime_real() - t0 < ticks) {}
}

// ---------------- production ----------------
__device__ __forceinline__ void ghmc_elem(float p, int t, unsigned int* s_hist,
                                          unsigned int copy_base)
{
    // g = |sigmoid(p) - t| = sigmoid(t ? -p : p)
    float q = __int_as_float(__float_as_int(p) ^ (t << 31));
    float e = __expf(-q);
    float g = __builtin_amdgcn_rcpf(1.0f + e);
    int b = min((int)(g * 30.0f), BINS - 1);
    unsigned int pkt = CNT_ONE | (unsigned int)(g * GSCALE);
    atomicAdd(&s_hist[copy_base + b], pkt);
}

__device__ __forceinline__ void ghmc_vec4(float4 p, int4 t, unsigned int* s_hist,
                                          unsigned int copy_base)
{
    ghmc_elem(p.x, t.x, s_hist, copy_base);
    ghmc_elem(p.y, t.y, s_hist, copy_base);
    ghmc_elem(p.z, t.z, s_hist, copy_base);
    ghmc_elem(p.w, t.w, s_hist, copy_base);
}

__device__ __forceinline__ void hist_init(unsigned int* s_hist, int tid)
{
    for (int i = tid; i < NCOPIES * CSTRIDE; i += BLOCK) s_hist[i] = 0u;
}

__device__ __forceinline__ void hist_flush(unsigned int* s_hist, int tid,
                                           unsigned int* g_cnt, float* g_gsum)
{
    if (tid < BINS) {
        unsigned int cnt = 0;
        float gs = 0.0f;
        #pragma unroll
        for (int c = 0; c < NCOPIES; ++c) {
            unsigned int v = s_hist[c * CSTRIDE + tid];
            cnt += v >> 23;
            gs  += (float)(v & GMASK);
        }
        atomicAdd(&g_cnt[tid], cnt);
        atomicAdd(&g_gsum[tid], gs * (1.0f / GSCALE));
    }
}

// wide: one straight-line pass, 2 float4-pairs per thread, 8192 blocks
__global__ __launch_bounds__(BLOCK) void ghmc_pass1_wide(
    const float* __restrict__ pred, const int* __restrict__ target,
    unsigned int* __restrict__ g_cnt, float* __restrict__ g_gsum)
{
    __shared__ unsigned int s_hist[NCOPIES * CSTRIDE];
    const int tid = threadIdx.x;
    const unsigned int copy_base = (((tid >> 6) << 4) + (tid & (CPW - 1))) * CSTRIDE;
    hist_init(s_hist, tid);
    __syncthreads();

    const float4* p4 = reinterpret_cast<const float4*>(pred);
    const int4*   t4 = reinterpret_cast<const int4*>(target);
    const int base = blockIdx.x * (BLOCK * 2) + tid;

    float4 pa = p4[base];
    float4 pb = p4[base + BLOCK];
    int4   ta = t4[base];
    int4   tb = t4[base + BLOCK];

    ghmc_vec4(pa, ta, s_hist, copy_base);
    ghmc_vec4(pb, tb, s_hist, copy_base);

    __syncthreads();
    hist_flush(s_hist, tid, g_cnt, g_gsum);
}

// generic fallback: any n
__global__ __launch_bounds__(BLOCK) void ghmc_pass1_gen(
    const float* __restrict__ pred, const int* __restrict__ target,
    unsigned int* __restrict__ g_cnt, float* __restrict__ g_gsum,
    int n4, int n)
{
    __shared__ unsigned int s_hist[NCOPIES * CSTRIDE];
    const int tid = threadIdx.x;
    const unsigned int copy_base = (((tid >> 6) << 4) + (tid & (CPW - 1))) * CSTRIDE;
    hist_init(s_hist, tid);
    __syncthreads();

    const int gid    = blockIdx.x * BLOCK + tid;
    const int stride = gridDim.x * BLOCK;
    for (int i = gid; i < n4; i += stride) {
        float4 p = reinterpret_cast<const float4*>(pred)[i];
        int4   t = reinterpret_cast<const int4*>(target)[i];
        ghmc_vec4(p, t, s_hist, copy_base);
    }
    if (blockIdx.x == 0) {
        for (int i = n4 * 4 + tid; i < n; i += BLOCK)
            ghmc_elem(pred[i], target[i], s_hist, copy_base);
    }

    __syncthreads();
    hist_flush(s_hist, tid, g_cnt, g_gsum);
}

__global__ __launch_bounds__(64) void ghmc_final(
    const unsigned int* __restrict__ counts, const float* __restrict__ gsums,
    const float* __restrict__ acc_sum, float* __restrict__ out, float total)
{
    const int tid = threadIdx.x;  // one wave of 64
    bool nonempty = (tid < BINS) && (counts[tid] > 0u);
    float n = fmaxf((float)__popcll(__ballot(nonempty)), 1.0f);

    float val = 0.0f;
    if (nonempty) {
        float c     = (float)counts[tid];   // = 2 * elements (reference histogram)
        float elems = 0.5f * c;
        float gmean = gsums[tid] / elems;
        // two-channel bce per element collapses to F(g); evaluate at bin mean
        float F = log1pf(expf(gmean)) + log1pf(expf(1.0f - gmean)) - 1.0f + gmean;
        float new_acc = 0.75f * acc_sum[tid] + 0.25f * c;
        float w = (total / fmaxf(new_acc, 1e-12f)) / n;
        val = w * elems * F;
    }
    #pragma unroll
    for (int off = 32; off > 0; off >>= 1) val += __shfl_down(val, off);
    if (tid == 0) out[0] = val / total;
}

extern "C" void kernel_launch(void* const* d_in, const int* in_sizes, int n_in,
                              void* d_out, int out_size, void* d_ws, size_t ws_size,
                              hipStream_t stream) {
    const float* pred    = (const float*)d_in[0];
    const float* acc_sum = (const float*)d_in[1];
    const int*   target  = (const int*)d_in[2];
    float* out = (float*)d_out;

    int n  = in_sizes[0];
    int n4 = n / 4;
    float total = fmaxf(2.0f * (float)n, 1.0f);

    unsigned int* g_cnt  = (unsigned int*)d_ws;
    float*        g_gsum = (float*)d_ws + BINS;

    hipMemsetAsync(d_ws, 0, 2 * BINS * sizeof(float), stream);

    // --- diagnostics: shader-clock spin (dur = 240000/SCLK_MHz us) and
    //     realtime spin (dur = 50 us exactly; validates mechanism) ---
    spin_shader_clk<<<1, 64, 0, stream>>>(240000ULL);
    spin_real_clk<<<1, 64, 0, stream>>>(5000ULL);

    if (n == WGRID * BLOCK * 8) {
        ghmc_pass1_wide<<<WGRID, BLOCK, 0, stream>>>(pred, target, g_cnt, g_gsum);
    } else {
        ghmc_pass1_gen<<<GGRID, BLOCK, 0, stream>>>(pred, target, g_cnt, g_gsum, n4, n);
    }
    ghmc_final<<<1, 64, 0, stream>>>(g_cnt, g_gsum, acc_sum, out, total);
}

// Round 8
// 43.767 us; speedup vs baseline: 9.4325x; 9.4325x over previous
//
#include <hip/hip_runtime.h>
#include <math.h>

#define BINS 30
#define BLOCK 256
#define GRID 512                        // few workgroups: per-WG overhead ~40ns*512 = 20us
#define ITERS 32                        // fast path: n4 == GRID*BLOCK*ITERS (N = 2^24)
#define GGRID 2048                      // generic fallback grid
#define CPW 16                          // histogram copies per wave (lane & 15)
#define NCOPIES 64                      // 4 waves * 16
#define CSTRIDE 31                      // 30 bins + 1 pad word (bank stagger)
// packed u32 payload: count in bits 21..31 (+2/elem, max 1024 < 2047),
// sum(g) in bits 0..20, 0.12 fixed point (512 elems/copy * 4095 < 2^21)
#define GSCALE 4096.0f
#define CNT_SHIFT 21
#define CNT_ONE (2u << CNT_SHIFT)
#define GMASK 0x1FFFFFu

// d_ws layout: [0..29] u32 counts, [30..59] f32 g-sums

__device__ __forceinline__ void ghmc_elem(float p, int t, unsigned int* s_hist,
                                          unsigned int copy_base)
{
    // g = |sigmoid(p) - t| = sigmoid(t ? -p : p)
    float q = __int_as_float(__float_as_int(p) ^ (t << 31));
    float e = __expf(-q);
    float g = __builtin_amdgcn_rcpf(1.0f + e);
    int b = min((int)(g * 30.0f), BINS - 1);
    unsigned int pkt = CNT_ONE | (unsigned int)(g * GSCALE);
    atomicAdd(&s_hist[copy_base + b], pkt);
}

__device__ __forceinline__ void ghmc_vec4(float4 p, int4 t, unsigned int* s_hist,
                                          unsigned int copy_base)
{
    ghmc_elem(p.x, t.x, s_hist, copy_base);
    ghmc_elem(p.y, t.y, s_hist, copy_base);
    ghmc_elem(p.z, t.z, s_hist, copy_base);
    ghmc_elem(p.w, t.w, s_hist, copy_base);
}

__device__ __forceinline__ void hist_init(unsigned int* s_hist, int tid)
{
    for (int i = tid; i < NCOPIES * CSTRIDE; i += BLOCK) s_hist[i] = 0u;
}

__device__ __forceinline__ void hist_flush(unsigned int* s_hist, int tid,
                                           unsigned int* g_cnt, float* g_gsum)
{
    if (tid < BINS) {
        unsigned int cnt = 0;
        float gs = 0.0f;
        #pragma unroll
        for (int c = 0; c < NCOPIES; ++c) {
            unsigned int v = s_hist[c * CSTRIDE + tid];
            cnt += v >> CNT_SHIFT;
            gs  += (float)(v & GMASK);
        }
        atomicAdd(&g_cnt[tid], cnt);
        atomicAdd(&g_gsum[tid], gs * (1.0f / GSCALE));
    }
}

// ---- fast path: exact N = GRID*BLOCK*4*ITERS, 3-deep register pipeline ----
__global__ __launch_bounds__(BLOCK) void ghmc_pass1_pipe(
    const float* __restrict__ pred, const int* __restrict__ target,
    unsigned int* __restrict__ g_cnt, float* __restrict__ g_gsum)
{
    __shared__ unsigned int s_hist[NCOPIES * CSTRIDE];
    const int tid = threadIdx.x;
    const unsigned int copy_base = (((tid >> 6) << 4) + (tid & (CPW - 1))) * CSTRIDE;
    hist_init(s_hist, tid);
    __syncthreads();

    const float4* p4 = reinterpret_cast<const float4*>(pred);
    const int4*   t4 = reinterpret_cast<const int4*>(target);
    const int stride = GRID * BLOCK;
    const int idx = blockIdx.x * BLOCK + tid;

    float4 pv[3];
    int4   tv[3];
    #pragma unroll
    for (int k = 0; k < 3; ++k) {
        pv[k] = p4[idx + k * stride];
        tv[k] = t4[idx + k * stride];
    }
    __builtin_amdgcn_sched_barrier(0);   // keep prologue loads hoisted

    #pragma unroll
    for (int k = 0; k < ITERS; ++k) {
        const int slot = k % 3;          // compile-time after full unroll
        ghmc_vec4(pv[slot], tv[slot], s_hist, copy_base);
        if (k + 3 < ITERS) {             // refill: lands 3 iterations later
            pv[slot] = p4[idx + (k + 3) * stride];
            tv[slot] = t4[idx + (k + 3) * stride];
        }
    }

    __syncthreads();
    hist_flush(s_hist, tid, g_cnt, g_gsum);
}

// ---- generic fallback: any n ----
__global__ __launch_bounds__(BLOCK) void ghmc_pass1_gen(
    const float* __restrict__ pred, const int* __restrict__ target,
    unsigned int* __restrict__ g_cnt, float* __restrict__ g_gsum,
    int n4, int n)
{
    __shared__ unsigned int s_hist[NCOPIES * CSTRIDE];
    const int tid = threadIdx.x;
    const unsigned int copy_base = (((tid >> 6) << 4) + (tid & (CPW - 1))) * CSTRIDE;
    hist_init(s_hist, tid);
    __syncthreads();

    const int gid    = blockIdx.x * BLOCK + tid;
    const int stride = gridDim.x * BLOCK;
    for (int i = gid; i < n4; i += stride) {
        float4 p = reinterpret_cast<const float4*>(pred)[i];
        int4   t = reinterpret_cast<const int4*>(target)[i];
        ghmc_vec4(p, t, s_hist, copy_base);
    }
    if (blockIdx.x == 0) {
        for (int i = n4 * 4 + tid; i < n; i += BLOCK)
            ghmc_elem(pred[i], target[i], s_hist, copy_base);
    }

    __syncthreads();
    hist_flush(s_hist, tid, g_cnt, g_gsum);
}

__global__ __launch_bounds__(64) void ghmc_final(
    const unsigned int* __restrict__ counts, const float* __restrict__ gsums,
    const float* __restrict__ acc_sum, float* __restrict__ out, float total)
{
    const int tid = threadIdx.x;  // one wave of 64
    bool nonempty = (tid < BINS) && (counts[tid] > 0u);
    float n = fmaxf((float)__popcll(__ballot(nonempty)), 1.0f);

    float val = 0.0f;
    if (nonempty) {
        float c     = (float)counts[tid];   // = 2 * elements (reference histogram)
        float elems = 0.5f * c;
        float gmean = gsums[tid] / elems;
        // two-channel bce per element collapses to F(g); evaluate at bin mean
        float F = log1pf(expf(gmean)) + log1pf(expf(1.0f - gmean)) - 1.0f + gmean;
        float new_acc = 0.75f * acc_sum[tid] + 0.25f * c;
        float w = (total / fmaxf(new_acc, 1e-12f)) / n;
        val = w * elems * F;
    }
    #pragma unroll
    for (int off = 32; off > 0; off >>= 1) val += __shfl_down(val, off);
    if (tid == 0) out[0] = val / total;
}

extern "C" void kernel_launch(void* const* d_in, const int* in_sizes, int n_in,
                              void* d_out, int out_size, void* d_ws, size_t ws_size,
                              hipStream_t stream) {
    const float* pred    = (const float*)d_in[0];
    const float* acc_sum = (const float*)d_in[1];
    const int*   target  = (const int*)d_in[2];
    float* out = (float*)d_out;

    int n  = in_sizes[0];
    int n4 = n / 4;
    float total = fmaxf(2.0f * (float)n, 1.0f);

    unsigned int* g_cnt  = (unsigned int*)d_ws;
    float*        g_gsum = (float*)d_ws + BINS;

    hipMemsetAsync(d_ws, 0, 2 * BINS * sizeof(float), stream);

    if (n4 == GRID * BLOCK * ITERS && n % 4 == 0) {
        ghmc_pass1_pipe<<<GRID, BLOCK, 0, stream>>>(pred, target, g_cnt, g_gsum);
    } else {
        ghmc_pass1_gen<<<GGRID, BLOCK, 0, stream>>>(pred, target, g_cnt, g_gsum, n4, n);
    }
    ghmc_final<<<1, 64, 0, stream>>>(g_cnt, g_gsum, acc_sum, out, total);
}